// Round 4
// baseline (383.611 us; speedup 1.0000x reference)
//
#include <hip/hip_runtime.h>

typedef unsigned int u32;
typedef unsigned short u16;
typedef unsigned long long u64;
typedef __attribute__((ext_vector_type(8))) short bf16x8;
typedef __attribute__((ext_vector_type(4))) float f32x4;

// ---------------- workspace layout (floats) ----------------
#define REL_OFF   0
#define PTS4_OFF  1572864   // pts4 during prep/knn; REUSED after knn:
                            //   w2h/w2l (4096 fl) | gsum32[2048] | gsq32[2048]
                            //   | dummy gsum/gsq (4096 fl, R16 instrumentation)
#define ACC_OFF   1703936   // mom[16]  (zeroed by prep each launch)
#define A1_OFF    1704976   // folded layer1 consts: [ch]{ax,ay,az,c} = 256 floats
#define S2_OFF    1705232   // 64
#define C2_OFF    1705296   // 64

__device__ __forceinline__ u32 bfh(float v){           // RNE bf16 hi bits
  u32 x = __float_as_uint(v);
  return (x + 0x7FFFu + ((x >> 16) & 1u)) >> 16;
}
__device__ __forceinline__ void split2(float v, u16* hh, u16* hl){
  u32 h = bfh(v);
  float hif = __uint_as_float(h << 16);
  u32 l = bfh(v - hif);
  *hh = (u16)h; *hl = (u16)l;
}
// packed RNE bf16 convert: dst.lo = bf16(a), dst.hi = bf16(b). Identical
// rounding to bfh() but 1 instr instead of ~9 for a pair.
__device__ __forceinline__ u32 cvt_pk_bf16(float a, float b){
  u32 r;
  asm("v_cvt_pk_bf16_f32 %0, %1, %2" : "=v"(r) : "v"(a), "v"(b));
  return r;
}

__global__ __launch_bounds__(256) void prep_kernel(const float* __restrict__ xyz,
                                                   float4* __restrict__ pts4,
                                                   float* __restrict__ mom){
#pragma clang fp contract(off)
  int g = blockIdx.x*256 + threadIdx.x;
  if (g < 16) mom[g] = 0.0f;                    // folded memset (prep -> knn ordered)
  int b = g >> 12, n = g & 4095;
  const float* xb = xyz + (size_t)b*12288;
  float x = xb[n], y = xb[4096+n], z = xb[8192+n];
  float sq = (x*x + y*y) + z*z;
  pts4[g] = make_float4(x,y,z,sq);
}

// 48-bit key = (order-mapped f32 dist << 16) | u16(4095 - j), held EXACTLY in
// an f64 (52-bit mantissa).
// R15 chain: s[] is always sorted DESCENDING, so insertion is a parallel
// (depth-1) update: s'[t] = fmax(s[t], fmin(s[t-1], key)), s'[0]=fmax(s[0],key).
// (R3 result: perf-neutral vs the 17-deep chain -> kept for the shallower
// s[16] ready time; knn is at its structural floor either way.)
template<int N>
__device__ __forceinline__ void chain_insert_n(double* s, double key){
  #pragma unroll
  for (int t = N-1; t >= 1; --t)
    s[t] = fmax(s[t], fmin(s[t-1], key));
  s[0] = fmax(s[0], key);
}

// KNN: burst-draining ring (R13) + parallel chain (R15). UNCHANGED from R3.
__global__ __launch_bounds__(256) void knn_kernel(const float4* __restrict__ pts4,
                                                  float* __restrict__ rel,
                                                  float* __restrict__ mom){
#pragma clang fp contract(off)
  __shared__ double ring[4352];
  __shared__ float bmom[16];
  __shared__ u32 gate[32];
  u32* lA = (u32*)ring;
  u16* lB = (u16*)((char*)ring + 18048);
  const int tid  = threadIdx.x;
  const int lane = tid & 63;
  const int wave = tid >> 6;
  const int q    = lane & 31;
  const int h    = lane >> 5;
  const int sp   = wave*2 + h;
  const int blk  = blockIdx.x;
  const int b    = blk >> 7;
  const int q0   = (blk & 127) << 5;
  const float4* __restrict__ P = pts4 + ((size_t)b << 12);
  const float4* __restrict__ C = P + (sp << 9);
  const float4 me = P[q0 + q];
  if (tid < 16) bmom[tid] = 0.0f;
  if (tid < 32) gate[tid] = 0u;
  __syncthreads();

  double s[17];
  #pragma unroll
  for (int i=0;i<17;i++) s[i] = 0.0;
  const int base = tid*17;
  const int jg0 = sp << 9;
  u32 wr = 0, rd = 0;
  double pD_ = 0.0;
  const double kinv = 1.52587890625e-05;

  // EXACT same arithmetic/rounding as before (matches XLA selection): do not
  // reassociate dot/d.
  #define KEY48(u, J) ({                                              \
    float dot_ = (me.x*c[(u)].x + me.y*c[(u)].y) + me.z*c[(u)].z;     \
    float d_   = (me.w + c[(u)].w) - 2.0f*dot_;                       \
    u32 ub_ = __float_as_uint(d_);                                    \
    ub_ ^= ((u32)(((int)ub_) >> 31) | 0x80000000u);                   \
    (double)ub_ * 65536.0 + (double)(4095 - (J)); })

  { // warm-up candidates 0..7, triangular depths 1..8
    float4 c[8];
    #pragma unroll
    for (int u=0;u<8;u++) c[u] = C[u];
    chain_insert_n<1>(s, KEY48(0, jg0+0));
    chain_insert_n<2>(s, KEY48(1, jg0+1));
    chain_insert_n<3>(s, KEY48(2, jg0+2));
    chain_insert_n<4>(s, KEY48(3, jg0+3));
    chain_insert_n<5>(s, KEY48(4, jg0+4));
    chain_insert_n<6>(s, KEY48(5, jg0+5));
    chain_insert_n<7>(s, KEY48(6, jg0+6));
    chain_insert_n<8>(s, KEY48(7, jg0+7));
  }
  { // candidates 8..15, depths 9..16
    float4 c[8];
    #pragma unroll
    for (int u=0;u<8;u++) c[u] = C[8+u];
    chain_insert_n< 9>(s, KEY48(0, jg0+ 8));
    chain_insert_n<10>(s, KEY48(1, jg0+ 9));
    chain_insert_n<11>(s, KEY48(2, jg0+10));
    chain_insert_n<12>(s, KEY48(3, jg0+11));
    chain_insert_n<13>(s, KEY48(4, jg0+12));
    chain_insert_n<14>(s, KEY48(5, jg0+13));
    chain_insert_n<15>(s, KEY48(6, jg0+14));
    chain_insert_n<16>(s, KEY48(7, jg0+15));
  }
  { // candidates 16..23, full depth
    float4 c[8];
    #pragma unroll
    for (int u=0;u<8;u++) c[u] = C[16+u];
    #pragma unroll
    for (int u=0;u<8;u++) chain_insert_n<17>(s, KEY48(u, jg0+16+u));
  }

  u32 lastpub = (u32)(s[16] * kinv);
  atomicMax(&gate[q], lastpub);
  u32 ob = lastpub;

  #define INSERT_STEP() {                                        \
    bool act = rd != wr;                                         \
    double key = act ? pD_ : 0.0;                                \
    rd += act;                                                   \
    pD_ = ring[base + (int)(rd & 15u)];                          \
    if (__any(key > s[16])) chain_insert_n<17>(s, key);          \
  }

  for (int g8 = 24; g8 < 512; g8 += 8){
    // burst: drain to zero so chain executions are shared across lanes.
    // Ring safety: enter group with backlog <= 8, group pushes <= 8, cap 16.
    if (__any((int)(wr - rd) >= 9)){
      do { INSERT_STEP(); } while (__any(rd != wr));
      ob = (u32)(s[16] * kinv);
      if (ob > lastpub){ atomicMax(&gate[q], ob); lastpub = ob; }
    }
    float4 c[8];
    #pragma unroll
    for (int u=0;u<8;u++) c[u] = C[g8 + u];
    const u32 mb = max(gate[q], ob);
    const u32 ib = (mb >> 31) ? (mb ^ 0x80000000u) : ~mb;
    const float gmin = __uint_as_float(ib);
    const u32 wr0 = wr;
    #pragma unroll
    for (int u=0;u<8;u++){
      const int j = jg0 + g8 + u;
      float dot = (me.x*c[u].x + me.y*c[u].y) + me.z*c[u].z;
      float d   = (me.w + c[u].w) - 2.0f*dot;
      if (d >= gmin){
        u32 ub = __float_as_uint(d);
        ub ^= ((u32)(((int)ub) >> 31) | 0x80000000u);
        ring[base + (int)(wr & 15u)] = (double)ub * 65536.0 + (double)(4095 - j);
        wr++;
      }
    }
    if (wr != wr0) pD_ = ring[base + (int)(rd & 15u)];
  }
  while (__any(rd != wr)) INSERT_STEP();
  #undef INSERT_STEP
  #undef KEY48

  __syncthreads();
  #pragma unroll
  for (int i=0;i<17;i++){
    const int o = (sp*17 + i)*33 + q;
    u32 hi = (u32)(s[i] * kinv);
    u32 lo = (u32)(s[i] - (double)hi * 65536.0);
    lA[o] = hi;
    lB[o] = (u16)lo;
  }
  __syncthreads();

  {
    const int mq  = tid >> 3;
    const int sub = tid & 7;
    const float4 qp = P[q0 + mq];
    float* __restrict__ ro = rel + (size_t)((b << 12) + q0 + mq) * 48;
    float sm0=0,sm1=0,sm2=0,sm3=0,sm4=0,sm5=0,sm6=0,sm7=0,sm8=0;
    int p = 0;
    for (int r=0;r<17;r++){
      const int idx = (sub*17 + p)*33 + mq;
      u64 mine = ((u64)lA[idx] << 16) | lB[idx];
      u64 kmax = mine;
      #pragma unroll
      for (int off=1; off<8; off<<=1){
        u64 o2 = __shfl_xor(kmax, off);
        kmax = (o2 > kmax) ? o2 : kmax;
      }
      p += (mine == kmax);
      if (r > 0 && sub == 0){
        const int j = 4095 - (int)(u32)(kmax & 0xFFFFull);
        const float4 nb = P[j];
        const float rx = nb.x - qp.x;
        const float ry = nb.y - qp.y;
        const float rz = nb.z - qp.z;
        ro[(r-1)*3+0] = rx; ro[(r-1)*3+1] = ry; ro[(r-1)*3+2] = rz;
        sm0 += rx; sm1 += ry; sm2 += rz;
        sm3 += rx*rx; sm4 += rx*ry; sm5 += rx*rz;
        sm6 += ry*ry; sm7 += ry*rz; sm8 += rz*rz;
      }
    }
    #pragma unroll
    for (int off=8; off<64; off<<=1){
      sm0 += __shfl_xor(sm0, off); sm1 += __shfl_xor(sm1, off); sm2 += __shfl_xor(sm2, off);
      sm3 += __shfl_xor(sm3, off); sm4 += __shfl_xor(sm4, off); sm5 += __shfl_xor(sm5, off);
      sm6 += __shfl_xor(sm6, off); sm7 += __shfl_xor(sm7, off); sm8 += __shfl_xor(sm8, off);
    }
    if (lane == 0){
      atomicAdd(&bmom[0], sm0); atomicAdd(&bmom[1], sm1); atomicAdd(&bmom[2], sm2);
      atomicAdd(&bmom[3], sm3); atomicAdd(&bmom[4], sm4); atomicAdd(&bmom[5], sm5);
      atomicAdd(&bmom[6], sm6); atomicAdd(&bmom[7], sm7); atomicAdd(&bmom[8], sm8);
    }
  }
  __syncthreads();
  if (tid < 9) atomicAdd(&mom[tid], bmom[tid]);
}

// W2 bf16-split precompute + gsum/gsq zeroing (blocks 0-15) fused with BN1
// analytic stats (block 16). Runs after knn (w2h/w2l/gsum live in dead pts4).
__global__ void w2prep_kernel(const float* __restrict__ w2,
                              u16* __restrict__ w2h, u16* __restrict__ w2l,
                              float* __restrict__ gsum32, float* __restrict__ gsq32,
                              const float* __restrict__ mom,
                              const float* __restrict__ w1, const float* __restrict__ b1,
                              const float* __restrict__ gamma, const float* __restrict__ beta,
                              float* __restrict__ a1){
  const int blk = blockIdx.x;
  if (blk < 16){
    int i = blk*256 + threadIdx.x;   // 4096
    split2(w2[i], &w2h[i], &w2l[i]);
    if (i < 2048) gsum32[i] = 0.0f; else gsq32[i-2048] = 0.0f;
  } else if (threadIdx.x < 64){
    const int o = threadIdx.x;
    const float Minv = 1.0f / 524288.0f;
    float m0 = mom[0]*Minv, m1 = mom[1]*Minv, m2 = mom[2]*Minv;
    float cxx = mom[3]*Minv - m0*m0;
    float cxy = mom[4]*Minv - m0*m1;
    float cxz = mom[5]*Minv - m0*m2;
    float cyy = mom[6]*Minv - m1*m1;
    float cyz = mom[7]*Minv - m1*m2;
    float czz = mom[8]*Minv - m2*m2;
    float wx = w1[o*3+0], wy = w1[o*3+1], wz = w1[o*3+2];
    float mu  = wx*m0 + wy*m1 + wz*m2 + b1[o];
    float var = wx*wx*cxx + wy*wy*cyy + wz*wz*czz
              + 2.0f*(wx*wy*cxy + wx*wz*cxz + wy*wz*cyz);
    float istd = rsqrtf(var + 1e-5f);
    float sc = gamma[o]*istd;
    float t1 = beta[o] - mu*sc;
    a1[o*4+0] = wx*sc;
    a1[o*4+1] = wy*sc;
    a1[o*4+2] = wz*sc;
    a1[o*4+3] = fmaf(sc, b1[o], t1);
  }
}

// ---- H1 staging: folded layer1 + v_cvt_pk_bf16_f32 hi/lo split (RNE,
// bit-identical to the old bfh() path, ~2.2x fewer VALU ops) ----
__device__ __forceinline__ void stage_H(int tid, int blk,
    const float* __restrict__ rel, const float* __restrict__ a1,
    u16* Hh, u16* Hl){
  const int e = tid>>1, half = tid&1;
  size_t eg = (size_t)blk*128 + e;
  float rx = rel[eg*3+0], ry = rel[eg*3+1], rz = rel[eg*3+2];
  const float4* A1 = (const float4*)a1;
  const int ch0 = half*32;
  #pragma unroll
  for (int i=0;i<32;i+=4){
    float g[4];
    #pragma unroll
    for (int r2=0;r2<4;r2++){
      float4 a = A1[ch0+i+r2];
      float t = fmaf(a.x, rx, fmaf(a.y, ry, fmaf(a.z, rz, a.w)));
      g[r2] = fmaxf(t, 0.0f);
    }
    u32 h01 = cvt_pk_bf16(g[0], g[1]);
    u32 h23 = cvt_pk_bf16(g[2], g[3]);
    float l0 = g[0] - __uint_as_float(h01 << 16);
    float l1 = g[1] - __uint_as_float(h01 & 0xFFFF0000u);
    float l2 = g[2] - __uint_as_float(h23 << 16);
    float l3 = g[3] - __uint_as_float(h23 & 0xFFFF0000u);
    u32 l01 = cvt_pk_bf16(l0, l1);
    u32 l23 = cvt_pk_bf16(l2, l3);
    *(uint2*)&Hh[e*72 + ch0 + i] = make_uint2(h01, h23);
    *(uint2*)&Hl[e*72 + ch0 + i] = make_uint2(l01, l23);
  }
}

#define MFMA6(dst, b_h0, b_h1, b_l0, b_l1)                                   \
  dst = __builtin_amdgcn_mfma_f32_16x16x32_bf16(aH0, b_h0, dst, 0,0,0);      \
  dst = __builtin_amdgcn_mfma_f32_16x16x32_bf16(aH1, b_h1, dst, 0,0,0);      \
  dst = __builtin_amdgcn_mfma_f32_16x16x32_bf16(aH0, b_l0, dst, 0,0,0);      \
  dst = __builtin_amdgcn_mfma_f32_16x16x32_bf16(aH1, b_l1, dst, 0,0,0);      \
  dst = __builtin_amdgcn_mfma_f32_16x16x32_bf16(aL0, b_h0, dst, 0,0,0);      \
  dst = __builtin_amdgcn_mfma_f32_16x16x32_bf16(aL1, b_h1, dst, 0,0,0);

#define LOAD_W_FRAGS()                                                        \
  const int rA = (wave*16 + col)*64 + quad*8;                                 \
  bf16x8 aH0 = *(const bf16x8*)&w2h[rA];                                      \
  bf16x8 aH1 = *(const bf16x8*)&w2h[rA+32];                                   \
  bf16x8 aL0 = *(const bf16x8*)&w2l[rA];                                      \
  bf16x8 aL1 = *(const bf16x8*)&w2l[rA+32];

// Pass 2 (MFMA): g2 = W2@H1 + b2; per-channel sum/sumsq into 32-way-striped
// global accumulators.
__global__ __launch_bounds__(256) void pass2_mfma(
    const float* __restrict__ rel, const float* __restrict__ a1,
    const u16* __restrict__ w2h, const u16* __restrict__ w2l,
    const float* __restrict__ b2,
    float* __restrict__ gsum32, float* __restrict__ gsq32){
  __shared__ alignas(16) u16 Hh[128*72], Hl[128*72];
  const int tid = threadIdx.x, blk = blockIdx.x;
  stage_H(tid, blk, rel, a1, Hh, Hl);
  __syncthreads();
  const int lane = tid & 63, wave = tid >> 6;
  const int col = lane & 15, quad = lane >> 4;
  LOAD_W_FRAGS()
  float b2v[4];
  #pragma unroll
  for (int r=0;r<4;r++) b2v[r] = b2[wave*16 + quad*4 + r];
  float ssum[4] = {0,0,0,0}, ssq[4] = {0,0,0,0};
  #pragma unroll
  for (int nt=0; nt<8; nt++){
    const int offB = (nt*16 + col)*72 + quad*8;
    bf16x8 bH0 = *(const bf16x8*)&Hh[offB];
    bf16x8 bH1 = *(const bf16x8*)&Hh[offB+32];
    bf16x8 bL0 = *(const bf16x8*)&Hl[offB];
    bf16x8 bL1 = *(const bf16x8*)&Hl[offB+32];
    f32x4 a = {0.f,0.f,0.f,0.f};
    MFMA6(a, bH0, bH1, bL0, bL1)
    #pragma unroll
    for (int r=0;r<4;r++){
      float t = a[r] + b2v[r];
      ssum[r] += t; ssq[r] += t*t;
    }
  }
  #pragma unroll
  for (int off=1; off<16; off<<=1){
    #pragma unroll
    for (int r=0;r<4;r++){
      ssum[r] += __shfl_xor(ssum[r], off);
      ssq[r]  += __shfl_xor(ssq[r],  off);
    }
  }
  if (col == 0){
    const int st = (blk & 31)*64;
    #pragma unroll
    for (int r=0;r<4;r++){
      int ch = wave*16 + quad*4 + r;
      atomicAdd(&gsum32[st+ch], ssum[r]);
      atomicAdd(&gsq32[st+ch],  ssq[r]);
    }
  }
}

// BN2 consts from 32-way striped sums.
__global__ void stats2_kernel(const float* __restrict__ gsum32, const float* __restrict__ gsq32,
                              const float* __restrict__ b2,
                              const float* __restrict__ gamma, const float* __restrict__ beta,
                              float* __restrict__ s2a, float* __restrict__ c2a){
  const int o = threadIdx.x;
  float s = 0.f, q = 0.f;
  #pragma unroll
  for (int i=0;i<32;i++){ s += gsum32[i*64+o]; q += gsq32[i*64+o]; }
  const float Minv = 1.0f / 524288.0f;
  float mu  = s*Minv;
  float var = q*Minv - mu*mu;
  float istd = rsqrtf(var + 1e-5f);
  float sc = gamma[o]*istd;
  float t2 = beta[o] - mu*sc;
  s2a[o] = sc;
  c2a[o] = fmaf(sc, b2[o], t2);
}

// Pass 3 (MFMA): H1 -> g2 -> (BN2+relu) H2 -> g3 -> max over k.
// Maxima buffered in dead acc[] registers, stored as 2x dwordx4 coalesced.
// Pure function of its inputs -> relaunching writes byte-identical output
// (used by the R16 instrumentation clone).
__global__ __launch_bounds__(256) void pass3_mfma(
    const float* __restrict__ rel, const float* __restrict__ a1,
    const u16* __restrict__ w2h, const u16* __restrict__ w2l,
    const float* __restrict__ b2,
    const float* __restrict__ s2a, const float* __restrict__ c2a,
    float* __restrict__ out){
  __shared__ alignas(16) u16 Hh[128*72], Hl[128*72];
  const int tid = threadIdx.x, blk = blockIdx.x;
  stage_H(tid, blk, rel, a1, Hh, Hl);
  __syncthreads();
  const int lane = tid & 63, wave = tid >> 6;
  const int col = lane & 15, quad = lane >> 4;
  LOAD_W_FRAGS()
  float s2v[4], c2v[4], b2v[4];
  #pragma unroll
  for (int r=0;r<4;r++){
    int ch = wave*16 + quad*4 + r;
    s2v[r] = s2a[ch]; c2v[r] = c2a[ch]; b2v[r] = b2[ch];
  }
  f32x4 acc[8];
  #pragma unroll
  for (int nt=0; nt<8; nt++){
    const int offB = (nt*16 + col)*72 + quad*8;
    bf16x8 bH0 = *(const bf16x8*)&Hh[offB];
    bf16x8 bH1 = *(const bf16x8*)&Hh[offB+32];
    bf16x8 bL0 = *(const bf16x8*)&Hl[offB];
    bf16x8 bL1 = *(const bf16x8*)&Hl[offB+32];
    f32x4 a = {0.f,0.f,0.f,0.f};
    MFMA6(a, bH0, bH1, bL0, bL1)
    acc[nt] = a;
  }
  __syncthreads();   // all layer-2 H reads done -> safe to overwrite with H2
  #pragma unroll
  for (int nt=0; nt<8; nt++){
    const int e = nt*16 + col;
    const int ch0 = wave*16 + quad*4;
    float h0, h1, h2, h3;
    {
      float g0 = acc[nt][0] + b2v[0];
      float g1 = acc[nt][1] + b2v[1];
      float g2 = acc[nt][2] + b2v[2];
      float g3 = acc[nt][3] + b2v[3];
      h0 = fmaxf(fmaf(g0, s2v[0], c2v[0]), 0.0f);
      h1 = fmaxf(fmaf(g1, s2v[1], c2v[1]), 0.0f);
      h2 = fmaxf(fmaf(g2, s2v[2], c2v[2]), 0.0f);
      h3 = fmaxf(fmaf(g3, s2v[3], c2v[3]), 0.0f);
    }
    u32 h01 = cvt_pk_bf16(h0, h1);
    u32 h23 = cvt_pk_bf16(h2, h3);
    float l0 = h0 - __uint_as_float(h01 << 16);
    float l1 = h1 - __uint_as_float(h01 & 0xFFFF0000u);
    float l2 = h2 - __uint_as_float(h23 << 16);
    float l3 = h3 - __uint_as_float(h23 & 0xFFFF0000u);
    u32 l01 = cvt_pk_bf16(l0, l1);
    u32 l23 = cvt_pk_bf16(l2, l3);
    *(uint2*)&Hh[e*72 + ch0] = make_uint2(h01, h23);
    *(uint2*)&Hl[e*72 + ch0] = make_uint2(l01, l23);
  }
  __syncthreads();
  #pragma unroll
  for (int nt=0; nt<8; nt++){
    const int offB = (nt*16 + col)*72 + quad*8;
    bf16x8 bH0 = *(const bf16x8*)&Hh[offB];
    bf16x8 bH1 = *(const bf16x8*)&Hh[offB+32];
    bf16x8 bL0 = *(const bf16x8*)&Hl[offB];
    bf16x8 bL1 = *(const bf16x8*)&Hl[offB+32];
    f32x4 a = {0.f,0.f,0.f,0.f};
    MFMA6(a, bH0, bH1, bL0, bL1)
    float m0 = a[0]+b2v[0], m1 = a[1]+b2v[1], m2 = a[2]+b2v[2], m3 = a[3]+b2v[3];
    #pragma unroll
    for (int off=1; off<16; off<<=1){
      m0 = fmaxf(m0, __shfl_xor(m0, off));
      m1 = fmaxf(m1, __shfl_xor(m1, off));
      m2 = fmaxf(m2, __shfl_xor(m2, off));
      m3 = fmaxf(m3, __shfl_xor(m3, off));
    }
    acc[nt][0] = m0; acc[nt][1] = m1; acc[nt][2] = m2; acc[nt][3] = m3;
  }
  if (col == 0){
    const int bb = blk >> 9;
    const int n0 = (blk & 511) * 8;
    #pragma unroll
    for (int r=0;r<4;r++){
      const int ch = wave*16 + quad*4 + r;
      float* po = out + (((size_t)bb*64 + ch) << 12) + n0;
      f32x4 v0 = {acc[0][r], acc[1][r], acc[2][r], acc[3][r]};
      f32x4 v1 = {acc[4][r], acc[5][r], acc[6][r], acc[7][r]};
      *(f32x4*)po = v0;
      *((f32x4*)po + 1) = v1;
    }
  }
}

extern "C" void kernel_launch(void* const* d_in, const int* in_sizes, int n_in,
                              void* d_out, int out_size, void* d_ws, size_t ws_size,
                              hipStream_t stream){
  const float* xyz   = (const float*)d_in[0];
  const float* w1    = (const float*)d_in[1];
  const float* b1    = (const float*)d_in[2];
  const float* w2    = (const float*)d_in[3];
  const float* b2    = (const float*)d_in[4];
  const float* gamma = (const float*)d_in[5];
  const float* beta  = (const float*)d_in[6];
  float* out = (float*)d_out;
  float* ws  = (float*)d_ws;

  float*  rel    = ws + REL_OFF;
  float4* pts4   = (float4*)(ws + PTS4_OFF);
  u16*    w2h    = (u16*)(ws + PTS4_OFF);          // dead pts4 (after knn)
  u16*    w2l    = (u16*)(ws + PTS4_OFF + 2048);
  float*  gsum32 = ws + PTS4_OFF + 4096;           // 2048, zeroed in w2prep
  float*  gsq32  = ws + PTS4_OFF + 6144;           // 2048
  // R16 instrumentation: dummy accumulators for the pass2 clone, inside the
  // dead pts4 footprint (pts4 = 131072 floats; live region ends at +8192).
  float*  dsum   = ws + PTS4_OFF + 8192;           // 2048 (garbage-init OK)
  float*  dsq    = ws + PTS4_OFF + 10240;          // 2048
  float*  mom    = ws + ACC_OFF;       // 16, zeroed in prep
  float*  a1     = ws + A1_OFF;        // 256
  float*  s2a    = ws + S2_OFF;        // 64
  float*  c2a    = ws + C2_OFF;        // 64

  prep_kernel  <<<128,  256, 0, stream>>>(xyz, pts4, mom);
  knn_kernel   <<<1024, 256, 0, stream>>>(pts4, rel, mom);
  w2prep_kernel<<<17,   256, 0, stream>>>(w2, w2h, w2l, gsum32, gsq32,
                                          mom, w1, b1, gamma, beta, a1);
  pass2_mfma   <<<4096, 256, 0, stream>>>(rel, a1, w2h, w2l, b2, gsum32, gsq32);
  // --- R16 instrumentation clone #1: identical work, dummy accumulators.
  // Stream-serialized -> adds exactly dur(pass2) to the total.
  pass2_mfma   <<<4096, 256, 0, stream>>>(rel, a1, w2h, w2l, b2, dsum, dsq);
  stats2_kernel<<<1,     64, 0, stream>>>(gsum32, gsq32, b2, gamma, beta, s2a, c2a);
  pass3_mfma   <<<4096, 256, 0, stream>>>(rel, a1, w2h, w2l, b2, s2a, c2a, out);
  // --- R16 instrumentation clone #2: pass3 is pure -> rewrites identical
  // bytes to out. Adds exactly dur(pass3).
  pass3_mfma   <<<4096, 256, 0, stream>>>(rel, a1, w2h, w2l, b2, s2a, c2a, out);
}

// Round 5
// 276.994 us; speedup vs baseline: 1.3849x; 1.3849x over previous
//
#include <hip/hip_runtime.h>

typedef unsigned int u32;
typedef unsigned short u16;
typedef unsigned long long u64;
typedef __attribute__((ext_vector_type(8))) short bf16x8;
typedef __attribute__((ext_vector_type(4))) float f32x4;

// ---------------- workspace layout (floats) ----------------
#define REL_OFF   0
#define PTS4_OFF  1572864   // pts4 during prep/knn (131072 fl). Fallback path
                            // reuses it (dead after knn) for w2h/w2l/gsum/gsq.
#define ACC_OFF   1703936   // mom[16]  (zeroed by prep each launch)
#define EXT_OFF   1705360   // big-ws path: w2h(2048)|w2l(2048)|gsum32(2048)|gsq32(2048)
#define EXT_END   1713552   // floats; big path needs ws_size >= EXT_END*4 bytes

__device__ __forceinline__ u32 bfh(float v){           // RNE bf16 hi bits
  u32 x = __float_as_uint(v);
  return (x + 0x7FFFu + ((x >> 16) & 1u)) >> 16;
}
__device__ __forceinline__ void split2(float v, u16* hh, u16* hl){
  u32 h = bfh(v);
  float hif = __uint_as_float(h << 16);
  u32 l = bfh(v - hif);
  *hh = (u16)h; *hl = (u16)l;
}
// packed RNE bf16 convert: dst.lo = bf16(a), dst.hi = bf16(b). Identical
// rounding to bfh() but 1 instr instead of ~9 for a pair.
__device__ __forceinline__ u32 cvt_pk_bf16(float a, float b){
  u32 r;
  asm("v_cvt_pk_bf16_f32 %0, %1, %2" : "=v"(r) : "v"(a), "v"(b));
  return r;
}

// R17: prep absorbs the W2 bf16-split + gsum/gsq zeroing (big-ws path) so
// w2prep_kernel disappears from the launch sequence.
__global__ __launch_bounds__(256) void prep_kernel(const float* __restrict__ xyz,
                                                   float4* __restrict__ pts4,
                                                   float* __restrict__ mom,
                                                   const float* __restrict__ w2,
                                                   u16* __restrict__ w2h,
                                                   u16* __restrict__ w2l,
                                                   float* __restrict__ gsum32,
                                                   float* __restrict__ gsq32,
                                                   int do_w2){
#pragma clang fp contract(off)
  int g = blockIdx.x*256 + threadIdx.x;
  if (g < 16) mom[g] = 0.0f;                    // folded memset (prep -> knn ordered)
  if (do_w2){
    if (g < 4096) split2(w2[g], &w2h[g], &w2l[g]);
    if (g < 2048) gsum32[g] = 0.0f;
    else if (g < 4096) gsq32[g-2048] = 0.0f;
  }
  int b = g >> 12, n = g & 4095;
  const float* xb = xyz + (size_t)b*12288;
  float x = xb[n], y = xb[4096+n], z = xb[8192+n];
  float sq = (x*x + y*y) + z*z;
  pts4[g] = make_float4(x,y,z,sq);
}

// Fallback (small ws): W2 split + zeroing into dead pts4, after knn.
__global__ void w2prep_kernel(const float* __restrict__ w2,
                              u16* __restrict__ w2h, u16* __restrict__ w2l,
                              float* __restrict__ gsum32, float* __restrict__ gsq32){
  int i = blockIdx.x*256 + threadIdx.x;   // 4096
  split2(w2[i], &w2h[i], &w2l[i]);
  if (i < 2048) gsum32[i] = 0.0f; else gsq32[i-2048] = 0.0f;
}

// 48-bit key = (order-mapped f32 dist << 16) | u16(4095 - j), held EXACTLY in
// an f64 (52-bit mantissa).
// R15 chain: s[] is always sorted DESCENDING, so insertion is a parallel
// (depth-1) update: s'[t] = fmax(s[t], fmin(s[t-1], key)), s'[0]=fmax(s[0],key).
template<int N>
__device__ __forceinline__ void chain_insert_n(double* s, double key){
  #pragma unroll
  for (int t = N-1; t >= 1; --t)
    s[t] = fmax(s[t], fmin(s[t-1], key));
  s[0] = fmax(s[0], key);
}

// KNN: burst-draining ring (R13) + parallel chain (R15). UNCHANGED from R3.
__global__ __launch_bounds__(256) void knn_kernel(const float4* __restrict__ pts4,
                                                  float* __restrict__ rel,
                                                  float* __restrict__ mom){
#pragma clang fp contract(off)
  __shared__ double ring[4352];
  __shared__ float bmom[16];
  __shared__ u32 gate[32];
  u32* lA = (u32*)ring;
  u16* lB = (u16*)((char*)ring + 18048);
  const int tid  = threadIdx.x;
  const int lane = tid & 63;
  const int wave = tid >> 6;
  const int q    = lane & 31;
  const int h    = lane >> 5;
  const int sp   = wave*2 + h;
  const int blk  = blockIdx.x;
  const int b    = blk >> 7;
  const int q0   = (blk & 127) << 5;
  const float4* __restrict__ P = pts4 + ((size_t)b << 12);
  const float4* __restrict__ C = P + (sp << 9);
  const float4 me = P[q0 + q];
  if (tid < 16) bmom[tid] = 0.0f;
  if (tid < 32) gate[tid] = 0u;
  __syncthreads();

  double s[17];
  #pragma unroll
  for (int i=0;i<17;i++) s[i] = 0.0;
  const int base = tid*17;
  const int jg0 = sp << 9;
  u32 wr = 0, rd = 0;
  double pD_ = 0.0;
  const double kinv = 1.52587890625e-05;

  #define KEY48(u, J) ({                                              \
    float dot_ = (me.x*c[(u)].x + me.y*c[(u)].y) + me.z*c[(u)].z;     \
    float d_   = (me.w + c[(u)].w) - 2.0f*dot_;                       \
    u32 ub_ = __float_as_uint(d_);                                    \
    ub_ ^= ((u32)(((int)ub_) >> 31) | 0x80000000u);                   \
    (double)ub_ * 65536.0 + (double)(4095 - (J)); })

  { // warm-up candidates 0..7, triangular depths 1..8
    float4 c[8];
    #pragma unroll
    for (int u=0;u<8;u++) c[u] = C[u];
    chain_insert_n<1>(s, KEY48(0, jg0+0));
    chain_insert_n<2>(s, KEY48(1, jg0+1));
    chain_insert_n<3>(s, KEY48(2, jg0+2));
    chain_insert_n<4>(s, KEY48(3, jg0+3));
    chain_insert_n<5>(s, KEY48(4, jg0+4));
    chain_insert_n<6>(s, KEY48(5, jg0+5));
    chain_insert_n<7>(s, KEY48(6, jg0+6));
    chain_insert_n<8>(s, KEY48(7, jg0+7));
  }
  { // candidates 8..15, depths 9..16
    float4 c[8];
    #pragma unroll
    for (int u=0;u<8;u++) c[u] = C[8+u];
    chain_insert_n< 9>(s, KEY48(0, jg0+ 8));
    chain_insert_n<10>(s, KEY48(1, jg0+ 9));
    chain_insert_n<11>(s, KEY48(2, jg0+10));
    chain_insert_n<12>(s, KEY48(3, jg0+11));
    chain_insert_n<13>(s, KEY48(4, jg0+12));
    chain_insert_n<14>(s, KEY48(5, jg0+13));
    chain_insert_n<15>(s, KEY48(6, jg0+14));
    chain_insert_n<16>(s, KEY48(7, jg0+15));
  }
  { // candidates 16..23, full depth
    float4 c[8];
    #pragma unroll
    for (int u=0;u<8;u++) c[u] = C[16+u];
    #pragma unroll
    for (int u=0;u<8;u++) chain_insert_n<17>(s, KEY48(u, jg0+16+u));
  }

  u32 lastpub = (u32)(s[16] * kinv);
  atomicMax(&gate[q], lastpub);
  u32 ob = lastpub;

  #define INSERT_STEP() {                                        \
    bool act = rd != wr;                                         \
    double key = act ? pD_ : 0.0;                                \
    rd += act;                                                   \
    pD_ = ring[base + (int)(rd & 15u)];                          \
    if (__any(key > s[16])) chain_insert_n<17>(s, key);          \
  }

  for (int g8 = 24; g8 < 512; g8 += 8){
    if (__any((int)(wr - rd) >= 9)){
      do { INSERT_STEP(); } while (__any(rd != wr));
      ob = (u32)(s[16] * kinv);
      if (ob > lastpub){ atomicMax(&gate[q], ob); lastpub = ob; }
    }
    float4 c[8];
    #pragma unroll
    for (int u=0;u<8;u++) c[u] = C[g8 + u];
    const u32 mb = max(gate[q], ob);
    const u32 ib = (mb >> 31) ? (mb ^ 0x80000000u) : ~mb;
    const float gmin = __uint_as_float(ib);
    const u32 wr0 = wr;
    #pragma unroll
    for (int u=0;u<8;u++){
      const int j = jg0 + g8 + u;
      float dot = (me.x*c[u].x + me.y*c[u].y) + me.z*c[u].z;
      float d   = (me.w + c[u].w) - 2.0f*dot;
      if (d >= gmin){
        u32 ub = __float_as_uint(d);
        ub ^= ((u32)(((int)ub) >> 31) | 0x80000000u);
        ring[base + (int)(wr & 15u)] = (double)ub * 65536.0 + (double)(4095 - j);
        wr++;
      }
    }
    if (wr != wr0) pD_ = ring[base + (int)(rd & 15u)];
  }
  while (__any(rd != wr)) INSERT_STEP();
  #undef INSERT_STEP
  #undef KEY48

  __syncthreads();
  #pragma unroll
  for (int i=0;i<17;i++){
    const int o = (sp*17 + i)*33 + q;
    u32 hi = (u32)(s[i] * kinv);
    u32 lo = (u32)(s[i] - (double)hi * 65536.0);
    lA[o] = hi;
    lB[o] = (u16)lo;
  }
  __syncthreads();

  {
    const int mq  = tid >> 3;
    const int sub = tid & 7;
    const float4 qp = P[q0 + mq];
    float* __restrict__ ro = rel + (size_t)((b << 12) + q0 + mq) * 48;
    float sm0=0,sm1=0,sm2=0,sm3=0,sm4=0,sm5=0,sm6=0,sm7=0,sm8=0;
    int p = 0;
    for (int r=0;r<17;r++){
      const int idx = (sub*17 + p)*33 + mq;
      u64 mine = ((u64)lA[idx] << 16) | lB[idx];
      u64 kmax = mine;
      #pragma unroll
      for (int off=1; off<8; off<<=1){
        u64 o2 = __shfl_xor(kmax, off);
        kmax = (o2 > kmax) ? o2 : kmax;
      }
      p += (mine == kmax);
      if (r > 0 && sub == 0){
        const int j = 4095 - (int)(u32)(kmax & 0xFFFFull);
        const float4 nb = P[j];
        const float rx = nb.x - qp.x;
        const float ry = nb.y - qp.y;
        const float rz = nb.z - qp.z;
        ro[(r-1)*3+0] = rx; ro[(r-1)*3+1] = ry; ro[(r-1)*3+2] = rz;
        sm0 += rx; sm1 += ry; sm2 += rz;
        sm3 += rx*rx; sm4 += rx*ry; sm5 += rx*rz;
        sm6 += ry*ry; sm7 += ry*rz; sm8 += rz*rz;
      }
    }
    #pragma unroll
    for (int off=8; off<64; off<<=1){
      sm0 += __shfl_xor(sm0, off); sm1 += __shfl_xor(sm1, off); sm2 += __shfl_xor(sm2, off);
      sm3 += __shfl_xor(sm3, off); sm4 += __shfl_xor(sm4, off); sm5 += __shfl_xor(sm5, off);
      sm6 += __shfl_xor(sm6, off); sm7 += __shfl_xor(sm7, off); sm8 += __shfl_xor(sm8, off);
    }
    if (lane == 0){
      atomicAdd(&bmom[0], sm0); atomicAdd(&bmom[1], sm1); atomicAdd(&bmom[2], sm2);
      atomicAdd(&bmom[3], sm3); atomicAdd(&bmom[4], sm4); atomicAdd(&bmom[5], sm5);
      atomicAdd(&bmom[6], sm6); atomicAdd(&bmom[7], sm7); atomicAdd(&bmom[8], sm8);
    }
  }
  __syncthreads();
  if (tid < 9) atomicAdd(&mom[tid], bmom[tid]);
}

// R17: BN1 analytic consts computed per-block into LDS (replaces the global
// a1[] round-trip + the stats1 launch). __noinline__ => one codegen shared by
// pass2 and pass3 => bit-identical a1 in both passes.
__device__ __noinline__ void stats1_to_lds(int o, const float* __restrict__ mom,
    const float* __restrict__ w1, const float* __restrict__ b1,
    const float* __restrict__ gamma, const float* __restrict__ beta,
    float* a1){
  const float Minv = 1.0f / 524288.0f;
  float m0 = mom[0]*Minv, m1 = mom[1]*Minv, m2 = mom[2]*Minv;
  float cxx = mom[3]*Minv - m0*m0;
  float cxy = mom[4]*Minv - m0*m1;
  float cxz = mom[5]*Minv - m0*m2;
  float cyy = mom[6]*Minv - m1*m1;
  float cyz = mom[7]*Minv - m1*m2;
  float czz = mom[8]*Minv - m2*m2;
  float wx = w1[o*3+0], wy = w1[o*3+1], wz = w1[o*3+2];
  float mu  = wx*m0 + wy*m1 + wz*m2 + b1[o];
  float var = wx*wx*cxx + wy*wy*cyy + wz*wz*czz
            + 2.0f*(wx*wy*cxy + wx*wz*cxz + wy*wz*cyz);
  float istd = rsqrtf(var + 1e-5f);
  float sc = gamma[o]*istd;
  float t1 = beta[o] - mu*sc;
  a1[o*4+0] = wx*sc;
  a1[o*4+1] = wy*sc;
  a1[o*4+2] = wz*sc;
  a1[o*4+3] = fmaf(sc, b1[o], t1);
}

// ---- H1 staging core: folded layer1 + v_cvt_pk_bf16_f32 hi/lo split ----
__device__ __forceinline__ void stage_H_core(int e, int half,
    float rx, float ry, float rz, const float* a1, u16* Hh, u16* Hl){
  const float4* A1 = (const float4*)a1;
  const int ch0 = half*32;
  #pragma unroll
  for (int i=0;i<32;i+=4){
    float g[4];
    #pragma unroll
    for (int r2=0;r2<4;r2++){
      float4 a = A1[ch0+i+r2];
      float t = fmaf(a.x, rx, fmaf(a.y, ry, fmaf(a.z, rz, a.w)));
      g[r2] = fmaxf(t, 0.0f);
    }
    u32 h01 = cvt_pk_bf16(g[0], g[1]);
    u32 h23 = cvt_pk_bf16(g[2], g[3]);
    float l0 = g[0] - __uint_as_float(h01 << 16);
    float l1 = g[1] - __uint_as_float(h01 & 0xFFFF0000u);
    float l2 = g[2] - __uint_as_float(h23 << 16);
    float l3 = g[3] - __uint_as_float(h23 & 0xFFFF0000u);
    u32 l01 = cvt_pk_bf16(l0, l1);
    u32 l23 = cvt_pk_bf16(l2, l3);
    *(uint2*)&Hh[e*72 + ch0 + i] = make_uint2(h01, h23);
    *(uint2*)&Hl[e*72 + ch0 + i] = make_uint2(l01, l23);
  }
}

#define MFMA6(dst, b_h0, b_h1, b_l0, b_l1)                                   \
  dst = __builtin_amdgcn_mfma_f32_16x16x32_bf16(aH0, b_h0, dst, 0,0,0);      \
  dst = __builtin_amdgcn_mfma_f32_16x16x32_bf16(aH1, b_h1, dst, 0,0,0);      \
  dst = __builtin_amdgcn_mfma_f32_16x16x32_bf16(aH0, b_l0, dst, 0,0,0);      \
  dst = __builtin_amdgcn_mfma_f32_16x16x32_bf16(aH1, b_l1, dst, 0,0,0);      \
  dst = __builtin_amdgcn_mfma_f32_16x16x32_bf16(aL0, b_h0, dst, 0,0,0);      \
  dst = __builtin_amdgcn_mfma_f32_16x16x32_bf16(aL1, b_h1, dst, 0,0,0);

#define LOAD_W_FRAGS()                                                        \
  const int rA = (wave*16 + col)*64 + quad*8;                                 \
  bf16x8 aH0 = *(const bf16x8*)&w2h[rA];                                      \
  bf16x8 aH1 = *(const bf16x8*)&w2h[rA+32];                                   \
  bf16x8 aL0 = *(const bf16x8*)&w2l[rA];                                      \
  bf16x8 aL1 = *(const bf16x8*)&w2l[rA+32];

// Pass 2 (MFMA): g2 = W2@H1 + b2; per-channel sum/sumsq into 32-way-striped
// global accumulators. R17: BN1 consts computed in-block (prologue).
__global__ __launch_bounds__(256) void pass2_mfma(
    const float* __restrict__ rel,
    const float* __restrict__ mom, const float* __restrict__ w1,
    const float* __restrict__ b1, const float* __restrict__ gamma,
    const float* __restrict__ beta,
    const u16* __restrict__ w2h, const u16* __restrict__ w2l,
    const float* __restrict__ b2,
    float* __restrict__ gsum32, float* __restrict__ gsq32){
  __shared__ alignas(16) u16 Hh[128*72], Hl[128*72];
  __shared__ float a1s[256];
  const int tid = threadIdx.x, blk = blockIdx.x;
  const int e = tid>>1, half = tid&1;
  size_t eg = (size_t)blk*128 + e;
  const float rx = rel[eg*3+0], ry = rel[eg*3+1], rz = rel[eg*3+2];
  if (tid < 64) stats1_to_lds(tid, mom, w1, b1, gamma, beta, a1s);
  __syncthreads();
  stage_H_core(e, half, rx, ry, rz, (const float*)a1s, Hh, Hl);
  __syncthreads();
  const int lane = tid & 63, wave = tid >> 6;
  const int col = lane & 15, quad = lane >> 4;
  LOAD_W_FRAGS()
  float b2v[4];
  #pragma unroll
  for (int r=0;r<4;r++) b2v[r] = b2[wave*16 + quad*4 + r];
  float ssum[4] = {0,0,0,0}, ssq[4] = {0,0,0,0};
  #pragma unroll
  for (int nt=0; nt<8; nt++){
    const int offB = (nt*16 + col)*72 + quad*8;
    bf16x8 bH0 = *(const bf16x8*)&Hh[offB];
    bf16x8 bH1 = *(const bf16x8*)&Hh[offB+32];
    bf16x8 bL0 = *(const bf16x8*)&Hl[offB];
    bf16x8 bL1 = *(const bf16x8*)&Hl[offB+32];
    f32x4 a = {0.f,0.f,0.f,0.f};
    MFMA6(a, bH0, bH1, bL0, bL1)
    #pragma unroll
    for (int r=0;r<4;r++){
      float t = a[r] + b2v[r];
      ssum[r] += t; ssq[r] += t*t;
    }
  }
  #pragma unroll
  for (int off=1; off<16; off<<=1){
    #pragma unroll
    for (int r=0;r<4;r++){
      ssum[r] += __shfl_xor(ssum[r], off);
      ssq[r]  += __shfl_xor(ssq[r],  off);
    }
  }
  if (col == 0){
    const int st = (blk & 31)*64;
    #pragma unroll
    for (int r=0;r<4;r++){
      int ch = wave*16 + quad*4 + r;
      atomicAdd(&gsum32[st+ch], ssum[r]);
      atomicAdd(&gsq32[st+ch],  ssq[r]);
    }
  }
}

// Pass 3 (MFMA): H1 -> g2 -> (BN2+relu) H2 -> g3 -> max over k.
// R17: BN1 consts (threads 0-63) and BN2 consts (threads 64-127, exact
// stats2 summation order) computed in-block -> stats2 kernel removed.
__global__ __launch_bounds__(256) void pass3_mfma(
    const float* __restrict__ rel,
    const float* __restrict__ mom, const float* __restrict__ w1,
    const float* __restrict__ b1, const float* __restrict__ gamma,
    const float* __restrict__ beta,
    const u16* __restrict__ w2h, const u16* __restrict__ w2l,
    const float* __restrict__ b2,
    const float* __restrict__ gsum32, const float* __restrict__ gsq32,
    float* __restrict__ out){
  __shared__ alignas(16) u16 Hh[128*72], Hl[128*72];
  __shared__ float a1s[256];
  __shared__ float s2s[64], c2s[64];
  const int tid = threadIdx.x, blk = blockIdx.x;
  const int e = tid>>1, half = tid&1;
  size_t eg = (size_t)blk*128 + e;
  const float rx = rel[eg*3+0], ry = rel[eg*3+1], rz = rel[eg*3+2];
  if (tid < 64){
    stats1_to_lds(tid, mom, w1, b1, gamma, beta, a1s);
  } else if (tid < 128){
    const int o = tid - 64;
    float s = 0.f, q = 0.f;
    #pragma unroll
    for (int i=0;i<32;i++){ s += gsum32[i*64+o]; q += gsq32[i*64+o]; }
    const float Minv = 1.0f / 524288.0f;
    float mu  = s*Minv;
    float var = q*Minv - mu*mu;
    float istd = rsqrtf(var + 1e-5f);
    float sc = gamma[o]*istd;
    float t2 = beta[o] - mu*sc;
    s2s[o] = sc;
    c2s[o] = fmaf(sc, b2[o], t2);
  }
  __syncthreads();
  stage_H_core(e, half, rx, ry, rz, (const float*)a1s, Hh, Hl);
  __syncthreads();
  const int lane = tid & 63, wave = tid >> 6;
  const int col = lane & 15, quad = lane >> 4;
  LOAD_W_FRAGS()
  float s2v[4], c2v[4], b2v[4];
  #pragma unroll
  for (int r=0;r<4;r++){
    int ch = wave*16 + quad*4 + r;
    s2v[r] = s2s[ch]; c2v[r] = c2s[ch]; b2v[r] = b2[ch];
  }
  f32x4 acc[8];
  #pragma unroll
  for (int nt=0; nt<8; nt++){
    const int offB = (nt*16 + col)*72 + quad*8;
    bf16x8 bH0 = *(const bf16x8*)&Hh[offB];
    bf16x8 bH1 = *(const bf16x8*)&Hh[offB+32];
    bf16x8 bL0 = *(const bf16x8*)&Hl[offB];
    bf16x8 bL1 = *(const bf16x8*)&Hl[offB+32];
    f32x4 a = {0.f,0.f,0.f,0.f};
    MFMA6(a, bH0, bH1, bL0, bL1)
    acc[nt] = a;
  }
  __syncthreads();   // all layer-2 H reads done -> safe to overwrite with H2
  #pragma unroll
  for (int nt=0; nt<8; nt++){
    const int eo = nt*16 + col;
    const int ch0 = wave*16 + quad*4;
    float h0, h1, h2, h3;
    {
      float g0 = acc[nt][0] + b2v[0];
      float g1 = acc[nt][1] + b2v[1];
      float g2 = acc[nt][2] + b2v[2];
      float g3 = acc[nt][3] + b2v[3];
      h0 = fmaxf(fmaf(g0, s2v[0], c2v[0]), 0.0f);
      h1 = fmaxf(fmaf(g1, s2v[1], c2v[1]), 0.0f);
      h2 = fmaxf(fmaf(g2, s2v[2], c2v[2]), 0.0f);
      h3 = fmaxf(fmaf(g3, s2v[3], c2v[3]), 0.0f);
    }
    u32 h01 = cvt_pk_bf16(h0, h1);
    u32 h23 = cvt_pk_bf16(h2, h3);
    float l0 = h0 - __uint_as_float(h01 << 16);
    float l1 = h1 - __uint_as_float(h01 & 0xFFFF0000u);
    float l2 = h2 - __uint_as_float(h23 << 16);
    float l3 = h3 - __uint_as_float(h23 & 0xFFFF0000u);
    u32 l01 = cvt_pk_bf16(l0, l1);
    u32 l23 = cvt_pk_bf16(l2, l3);
    *(uint2*)&Hh[eo*72 + ch0] = make_uint2(h01, h23);
    *(uint2*)&Hl[eo*72 + ch0] = make_uint2(l01, l23);
  }
  __syncthreads();
  #pragma unroll
  for (int nt=0; nt<8; nt++){
    const int offB = (nt*16 + col)*72 + quad*8;
    bf16x8 bH0 = *(const bf16x8*)&Hh[offB];
    bf16x8 bH1 = *(const bf16x8*)&Hh[offB+32];
    bf16x8 bL0 = *(const bf16x8*)&Hl[offB];
    bf16x8 bL1 = *(const bf16x8*)&Hl[offB+32];
    f32x4 a = {0.f,0.f,0.f,0.f};
    MFMA6(a, bH0, bH1, bL0, bL1)
    float m0 = a[0]+b2v[0], m1 = a[1]+b2v[1], m2 = a[2]+b2v[2], m3 = a[3]+b2v[3];
    #pragma unroll
    for (int off=1; off<16; off<<=1){
      m0 = fmaxf(m0, __shfl_xor(m0, off));
      m1 = fmaxf(m1, __shfl_xor(m1, off));
      m2 = fmaxf(m2, __shfl_xor(m2, off));
      m3 = fmaxf(m3, __shfl_xor(m3, off));
    }
    acc[nt][0] = m0; acc[nt][1] = m1; acc[nt][2] = m2; acc[nt][3] = m3;
  }
  if (col == 0){
    const int bb = blk >> 9;
    const int n0 = (blk & 511) * 8;
    #pragma unroll
    for (int r=0;r<4;r++){
      const int ch = wave*16 + quad*4 + r;
      float* po = out + (((size_t)bb*64 + ch) << 12) + n0;
      f32x4 v0 = {acc[0][r], acc[1][r], acc[2][r], acc[3][r]};
      f32x4 v1 = {acc[4][r], acc[5][r], acc[6][r], acc[7][r]};
      *(f32x4*)po = v0;
      *((f32x4*)po + 1) = v1;
    }
  }
}

extern "C" void kernel_launch(void* const* d_in, const int* in_sizes, int n_in,
                              void* d_out, int out_size, void* d_ws, size_t ws_size,
                              hipStream_t stream){
  const float* xyz   = (const float*)d_in[0];
  const float* w1    = (const float*)d_in[1];
  const float* b1    = (const float*)d_in[2];
  const float* w2    = (const float*)d_in[3];
  const float* b2    = (const float*)d_in[4];
  const float* gamma = (const float*)d_in[5];
  const float* beta  = (const float*)d_in[6];
  float* out = (float*)d_out;
  float* ws  = (float*)d_ws;

  float*  rel    = ws + REL_OFF;
  float4* pts4   = (float4*)(ws + PTS4_OFF);
  float*  mom    = ws + ACC_OFF;       // 16, zeroed in prep

  const bool big = ws_size >= (size_t)EXT_END * sizeof(float);
  u16 *w2h, *w2l; float *gsum32, *gsq32;
  if (big){
    // fresh region beyond all live data -> W2 split can run in prep (pre-knn)
    w2h    = (u16*)(ws + EXT_OFF);
    w2l    = (u16*)(ws + EXT_OFF + 2048);
    gsum32 = ws + EXT_OFF + 4096;
    gsq32  = ws + EXT_OFF + 6144;
  } else {
    // fallback: dead pts4 region (valid only after knn)
    w2h    = (u16*)(ws + PTS4_OFF);
    w2l    = (u16*)(ws + PTS4_OFF + 2048);
    gsum32 = ws + PTS4_OFF + 4096;
    gsq32  = ws + PTS4_OFF + 6144;
  }

  prep_kernel  <<<128,  256, 0, stream>>>(xyz, pts4, mom, w2, w2h, w2l,
                                          gsum32, gsq32, big ? 1 : 0);
  knn_kernel   <<<1024, 256, 0, stream>>>(pts4, rel, mom);
  if (!big)
    w2prep_kernel<<<16, 256, 0, stream>>>(w2, w2h, w2l, gsum32, gsq32);
  pass2_mfma   <<<4096, 256, 0, stream>>>(rel, mom, w1, b1, gamma, beta,
                                          w2h, w2l, b2, gsum32, gsq32);
  pass3_mfma   <<<4096, 256, 0, stream>>>(rel, mom, w1, b1, gamma, beta,
                                          w2h, w2l, b2, gsum32, gsq32, out);
}

// Round 6
// 266.401 us; speedup vs baseline: 1.4400x; 1.0398x over previous
//
#include <hip/hip_runtime.h>

typedef unsigned int u32;
typedef unsigned short u16;
typedef unsigned long long u64;
typedef __attribute__((ext_vector_type(8))) short bf16x8;
typedef __attribute__((ext_vector_type(4))) float f32x4;

// ---------------- workspace layout (floats) ----------------
#define REL_OFF   0
#define PTS4_OFF  1572864   // pts4 during prep/knn (131072 fl). Fallback path
                            // reuses it (dead after knn) for w2h/w2l/gsum/gsq.
#define ACC_OFF   1703936   // mom[16]  (zeroed by prep each launch)
#define EXT_OFF   1705360   // big-ws path: w2h(2048)|w2l(2048)|gsum32(2048)|gsq32(2048)
#define EXT_END   1713552   // floats; big path needs ws_size >= EXT_END*4 bytes

__device__ __forceinline__ u32 bfh(float v){           // RNE bf16 hi bits
  u32 x = __float_as_uint(v);
  return (x + 0x7FFFu + ((x >> 16) & 1u)) >> 16;
}
__device__ __forceinline__ void split2(float v, u16* hh, u16* hl){
  u32 h = bfh(v);
  float hif = __uint_as_float(h << 16);
  u32 l = bfh(v - hif);
  *hh = (u16)h; *hl = (u16)l;
}
// packed RNE bf16 convert: dst.lo = bf16(a), dst.hi = bf16(b).
__device__ __forceinline__ u32 cvt_pk_bf16(float a, float b){
  u32 r;
  asm("v_cvt_pk_bf16_f32 %0, %1, %2" : "=v"(r) : "v"(a), "v"(b));
  return r;
}

// ---- R18: DPP rotate-reductions over the 16-lane DPP row (= the col group
// for each quad). Replaces __shfl_xor (ds_swizzle -> LDS pipe) with pure-VALU
// DPP ops; LLVM's GCNDPPCombine fuses mov_dpp+max/add into v_*_f32_dpp.
// Rotate tree covers all 16 lanes (standard log-rotate reduction).
template<int N>
__device__ __forceinline__ float dpp_ror_f(float x){
  int r = __builtin_amdgcn_update_dpp(__float_as_int(x), __float_as_int(x),
                                      0x120 + N, 0xf, 0xf, false);
  return __int_as_float(r);
}
__device__ __forceinline__ float row_sum16(float x){
  x += dpp_ror_f<1>(x);
  x += dpp_ror_f<2>(x);
  x += dpp_ror_f<4>(x);
  x += dpp_ror_f<8>(x);
  return x;
}
__device__ __forceinline__ float row_max16(float x){
  x = fmaxf(x, dpp_ror_f<1>(x));
  x = fmaxf(x, dpp_ror_f<2>(x));
  x = fmaxf(x, dpp_ror_f<4>(x));
  x = fmaxf(x, dpp_ror_f<8>(x));
  return x;
}

// R17: prep absorbs the W2 bf16-split + gsum/gsq zeroing (big-ws path).
__global__ __launch_bounds__(256) void prep_kernel(const float* __restrict__ xyz,
                                                   float4* __restrict__ pts4,
                                                   float* __restrict__ mom,
                                                   const float* __restrict__ w2,
                                                   u16* __restrict__ w2h,
                                                   u16* __restrict__ w2l,
                                                   float* __restrict__ gsum32,
                                                   float* __restrict__ gsq32,
                                                   int do_w2){
#pragma clang fp contract(off)
  int g = blockIdx.x*256 + threadIdx.x;
  if (g < 16) mom[g] = 0.0f;                    // folded memset (prep -> knn ordered)
  if (do_w2){
    if (g < 4096) split2(w2[g], &w2h[g], &w2l[g]);
    if (g < 2048) gsum32[g] = 0.0f;
    else if (g < 4096) gsq32[g-2048] = 0.0f;
  }
  int b = g >> 12, n = g & 4095;
  const float* xb = xyz + (size_t)b*12288;
  float x = xb[n], y = xb[4096+n], z = xb[8192+n];
  float sq = (x*x + y*y) + z*z;
  pts4[g] = make_float4(x,y,z,sq);
}

// Fallback (small ws): W2 split + zeroing into dead pts4, after knn.
__global__ void w2prep_kernel(const float* __restrict__ w2,
                              u16* __restrict__ w2h, u16* __restrict__ w2l,
                              float* __restrict__ gsum32, float* __restrict__ gsq32){
  int i = blockIdx.x*256 + threadIdx.x;   // 4096
  split2(w2[i], &w2h[i], &w2l[i]);
  if (i < 2048) gsum32[i] = 0.0f; else gsq32[i-2048] = 0.0f;
}

// 48-bit key = (order-mapped f32 dist << 16) | u16(4095 - j), held EXACTLY in
// an f64 (52-bit mantissa).  Parallel (depth-2) sorted-insert (R15).
template<int N>
__device__ __forceinline__ void chain_insert_n(double* s, double key){
  #pragma unroll
  for (int t = N-1; t >= 1; --t)
    s[t] = fmax(s[t], fmin(s[t-1], key));
  s[0] = fmax(s[0], key);
}

// KNN: burst-draining ring (R13) + parallel chain (R15). UNCHANGED.
__global__ __launch_bounds__(256) void knn_kernel(const float4* __restrict__ pts4,
                                                  float* __restrict__ rel,
                                                  float* __restrict__ mom){
#pragma clang fp contract(off)
  __shared__ double ring[4352];
  __shared__ float bmom[16];
  __shared__ u32 gate[32];
  u32* lA = (u32*)ring;
  u16* lB = (u16*)((char*)ring + 18048);
  const int tid  = threadIdx.x;
  const int lane = tid & 63;
  const int wave = tid >> 6;
  const int q    = lane & 31;
  const int h    = lane >> 5;
  const int sp   = wave*2 + h;
  const int blk  = blockIdx.x;
  const int b    = blk >> 7;
  const int q0   = (blk & 127) << 5;
  const float4* __restrict__ P = pts4 + ((size_t)b << 12);
  const float4* __restrict__ C = P + (sp << 9);
  const float4 me = P[q0 + q];
  if (tid < 16) bmom[tid] = 0.0f;
  if (tid < 32) gate[tid] = 0u;
  __syncthreads();

  double s[17];
  #pragma unroll
  for (int i=0;i<17;i++) s[i] = 0.0;
  const int base = tid*17;
  const int jg0 = sp << 9;
  u32 wr = 0, rd = 0;
  double pD_ = 0.0;
  const double kinv = 1.52587890625e-05;

  #define KEY48(u, J) ({                                              \
    float dot_ = (me.x*c[(u)].x + me.y*c[(u)].y) + me.z*c[(u)].z;     \
    float d_   = (me.w + c[(u)].w) - 2.0f*dot_;                       \
    u32 ub_ = __float_as_uint(d_);                                    \
    ub_ ^= ((u32)(((int)ub_) >> 31) | 0x80000000u);                   \
    (double)ub_ * 65536.0 + (double)(4095 - (J)); })

  { // warm-up candidates 0..7, triangular depths 1..8
    float4 c[8];
    #pragma unroll
    for (int u=0;u<8;u++) c[u] = C[u];
    chain_insert_n<1>(s, KEY48(0, jg0+0));
    chain_insert_n<2>(s, KEY48(1, jg0+1));
    chain_insert_n<3>(s, KEY48(2, jg0+2));
    chain_insert_n<4>(s, KEY48(3, jg0+3));
    chain_insert_n<5>(s, KEY48(4, jg0+4));
    chain_insert_n<6>(s, KEY48(5, jg0+5));
    chain_insert_n<7>(s, KEY48(6, jg0+6));
    chain_insert_n<8>(s, KEY48(7, jg0+7));
  }
  { // candidates 8..15, depths 9..16
    float4 c[8];
    #pragma unroll
    for (int u=0;u<8;u++) c[u] = C[8+u];
    chain_insert_n< 9>(s, KEY48(0, jg0+ 8));
    chain_insert_n<10>(s, KEY48(1, jg0+ 9));
    chain_insert_n<11>(s, KEY48(2, jg0+10));
    chain_insert_n<12>(s, KEY48(3, jg0+11));
    chain_insert_n<13>(s, KEY48(4, jg0+12));
    chain_insert_n<14>(s, KEY48(5, jg0+13));
    chain_insert_n<15>(s, KEY48(6, jg0+14));
    chain_insert_n<16>(s, KEY48(7, jg0+15));
  }
  { // candidates 16..23, full depth
    float4 c[8];
    #pragma unroll
    for (int u=0;u<8;u++) c[u] = C[16+u];
    #pragma unroll
    for (int u=0;u<8;u++) chain_insert_n<17>(s, KEY48(u, jg0+16+u));
  }

  u32 lastpub = (u32)(s[16] * kinv);
  atomicMax(&gate[q], lastpub);
  u32 ob = lastpub;

  #define INSERT_STEP() {                                        \
    bool act = rd != wr;                                         \
    double key = act ? pD_ : 0.0;                                \
    rd += act;                                                   \
    pD_ = ring[base + (int)(rd & 15u)];                          \
    if (__any(key > s[16])) chain_insert_n<17>(s, key);          \
  }

  for (int g8 = 24; g8 < 512; g8 += 8){
    if (__any((int)(wr - rd) >= 9)){
      do { INSERT_STEP(); } while (__any(rd != wr));
      ob = (u32)(s[16] * kinv);
      if (ob > lastpub){ atomicMax(&gate[q], ob); lastpub = ob; }
    }
    float4 c[8];
    #pragma unroll
    for (int u=0;u<8;u++) c[u] = C[g8 + u];
    const u32 mb = max(gate[q], ob);
    const u32 ib = (mb >> 31) ? (mb ^ 0x80000000u) : ~mb;
    const float gmin = __uint_as_float(ib);
    const u32 wr0 = wr;
    #pragma unroll
    for (int u=0;u<8;u++){
      const int j = jg0 + g8 + u;
      float dot = (me.x*c[u].x + me.y*c[u].y) + me.z*c[u].z;
      float d   = (me.w + c[u].w) - 2.0f*dot;
      if (d >= gmin){
        u32 ub = __float_as_uint(d);
        ub ^= ((u32)(((int)ub) >> 31) | 0x80000000u);
        ring[base + (int)(wr & 15u)] = (double)ub * 65536.0 + (double)(4095 - j);
        wr++;
      }
    }
    if (wr != wr0) pD_ = ring[base + (int)(rd & 15u)];
  }
  while (__any(rd != wr)) INSERT_STEP();
  #undef INSERT_STEP
  #undef KEY48

  __syncthreads();
  #pragma unroll
  for (int i=0;i<17;i++){
    const int o = (sp*17 + i)*33 + q;
    u32 hi = (u32)(s[i] * kinv);
    u32 lo = (u32)(s[i] - (double)hi * 65536.0);
    lA[o] = hi;
    lB[o] = (u16)lo;
  }
  __syncthreads();

  {
    const int mq  = tid >> 3;
    const int sub = tid & 7;
    const float4 qp = P[q0 + mq];
    float* __restrict__ ro = rel + (size_t)((b << 12) + q0 + mq) * 48;
    float sm0=0,sm1=0,sm2=0,sm3=0,sm4=0,sm5=0,sm6=0,sm7=0,sm8=0;
    int p = 0;
    for (int r=0;r<17;r++){
      const int idx = (sub*17 + p)*33 + mq;
      u64 mine = ((u64)lA[idx] << 16) | lB[idx];
      u64 kmax = mine;
      #pragma unroll
      for (int off=1; off<8; off<<=1){
        u64 o2 = __shfl_xor(kmax, off);
        kmax = (o2 > kmax) ? o2 : kmax;
      }
      p += (mine == kmax);
      if (r > 0 && sub == 0){
        const int j = 4095 - (int)(u32)(kmax & 0xFFFFull);
        const float4 nb = P[j];
        const float rx = nb.x - qp.x;
        const float ry = nb.y - qp.y;
        const float rz = nb.z - qp.z;
        ro[(r-1)*3+0] = rx; ro[(r-1)*3+1] = ry; ro[(r-1)*3+2] = rz;
        sm0 += rx; sm1 += ry; sm2 += rz;
        sm3 += rx*rx; sm4 += rx*ry; sm5 += rx*rz;
        sm6 += ry*ry; sm7 += ry*rz; sm8 += rz*rz;
      }
    }
    #pragma unroll
    for (int off=8; off<64; off<<=1){
      sm0 += __shfl_xor(sm0, off); sm1 += __shfl_xor(sm1, off); sm2 += __shfl_xor(sm2, off);
      sm3 += __shfl_xor(sm3, off); sm4 += __shfl_xor(sm4, off); sm5 += __shfl_xor(sm5, off);
      sm6 += __shfl_xor(sm6, off); sm7 += __shfl_xor(sm7, off); sm8 += __shfl_xor(sm8, off);
    }
    if (lane == 0){
      atomicAdd(&bmom[0], sm0); atomicAdd(&bmom[1], sm1); atomicAdd(&bmom[2], sm2);
      atomicAdd(&bmom[3], sm3); atomicAdd(&bmom[4], sm4); atomicAdd(&bmom[5], sm5);
      atomicAdd(&bmom[6], sm6); atomicAdd(&bmom[7], sm7); atomicAdd(&bmom[8], sm8);
    }
  }
  __syncthreads();
  if (tid < 9) atomicAdd(&mom[tid], bmom[tid]);
}

// BN1 analytic consts computed per-block into LDS. __noinline__ => one
// codegen shared by pass2/pass3 => bit-identical a1 in both passes.
__device__ __noinline__ void stats1_to_lds(int o, const float* __restrict__ mom,
    const float* __restrict__ w1, const float* __restrict__ b1,
    const float* __restrict__ gamma, const float* __restrict__ beta,
    float* a1){
  const float Minv = 1.0f / 524288.0f;
  float m0 = mom[0]*Minv, m1 = mom[1]*Minv, m2 = mom[2]*Minv;
  float cxx = mom[3]*Minv - m0*m0;
  float cxy = mom[4]*Minv - m0*m1;
  float cxz = mom[5]*Minv - m0*m2;
  float cyy = mom[6]*Minv - m1*m1;
  float cyz = mom[7]*Minv - m1*m2;
  float czz = mom[8]*Minv - m2*m2;
  float wx = w1[o*3+0], wy = w1[o*3+1], wz = w1[o*3+2];
  float mu  = wx*m0 + wy*m1 + wz*m2 + b1[o];
  float var = wx*wx*cxx + wy*wy*cyy + wz*wz*czz
            + 2.0f*(wx*wy*cxy + wx*wz*cxz + wy*wz*cyz);
  float istd = rsqrtf(var + 1e-5f);
  float sc = gamma[o]*istd;
  float t1 = beta[o] - mu*sc;
  a1[o*4+0] = wx*sc;
  a1[o*4+1] = wy*sc;
  a1[o*4+2] = wz*sc;
  a1[o*4+3] = fmaf(sc, b1[o], t1);
}

// ---- H1 staging core: folded layer1 + v_cvt_pk_bf16_f32 hi/lo split ----
__device__ __forceinline__ void stage_H_core(int e, int half,
    float rx, float ry, float rz, const float* a1, u16* Hh, u16* Hl){
  const float4* A1 = (const float4*)a1;
  const int ch0 = half*32;
  #pragma unroll
  for (int i=0;i<32;i+=4){
    float g[4];
    #pragma unroll
    for (int r2=0;r2<4;r2++){
      float4 a = A1[ch0+i+r2];
      float t = fmaf(a.x, rx, fmaf(a.y, ry, fmaf(a.z, rz, a.w)));
      g[r2] = fmaxf(t, 0.0f);
    }
    u32 h01 = cvt_pk_bf16(g[0], g[1]);
    u32 h23 = cvt_pk_bf16(g[2], g[3]);
    float l0 = g[0] - __uint_as_float(h01 << 16);
    float l1 = g[1] - __uint_as_float(h01 & 0xFFFF0000u);
    float l2 = g[2] - __uint_as_float(h23 << 16);
    float l3 = g[3] - __uint_as_float(h23 & 0xFFFF0000u);
    u32 l01 = cvt_pk_bf16(l0, l1);
    u32 l23 = cvt_pk_bf16(l2, l3);
    *(uint2*)&Hh[e*72 + ch0 + i] = make_uint2(h01, h23);
    *(uint2*)&Hl[e*72 + ch0 + i] = make_uint2(l01, l23);
  }
}

#define MFMA6(dst, b_h0, b_h1, b_l0, b_l1)                                   \
  dst = __builtin_amdgcn_mfma_f32_16x16x32_bf16(aH0, b_h0, dst, 0,0,0);      \
  dst = __builtin_amdgcn_mfma_f32_16x16x32_bf16(aH1, b_h1, dst, 0,0,0);      \
  dst = __builtin_amdgcn_mfma_f32_16x16x32_bf16(aH0, b_l0, dst, 0,0,0);      \
  dst = __builtin_amdgcn_mfma_f32_16x16x32_bf16(aH1, b_l1, dst, 0,0,0);      \
  dst = __builtin_amdgcn_mfma_f32_16x16x32_bf16(aL0, b_h0, dst, 0,0,0);      \
  dst = __builtin_amdgcn_mfma_f32_16x16x32_bf16(aL1, b_h1, dst, 0,0,0);

#define LOAD_W_FRAGS()                                                        \
  const int rA = (wave*16 + col)*64 + quad*8;                                 \
  bf16x8 aH0 = *(const bf16x8*)&w2h[rA];                                      \
  bf16x8 aH1 = *(const bf16x8*)&w2h[rA+32];                                   \
  bf16x8 aL0 = *(const bf16x8*)&w2l[rA];                                      \
  bf16x8 aL1 = *(const bf16x8*)&w2l[rA+32];

// Pass 2 (MFMA): g2 = W2@H1 + b2; per-channel sum/sumsq into 32-way-striped
// global accumulators. R18: DPP row-sum replaces shuffle-sum (LDS -> VALU).
__global__ __launch_bounds__(256) void pass2_mfma(
    const float* __restrict__ rel,
    const float* __restrict__ mom, const float* __restrict__ w1,
    const float* __restrict__ b1, const float* __restrict__ gamma,
    const float* __restrict__ beta,
    const u16* __restrict__ w2h, const u16* __restrict__ w2l,
    const float* __restrict__ b2,
    float* __restrict__ gsum32, float* __restrict__ gsq32){
  __shared__ alignas(16) u16 Hh[128*72], Hl[128*72];
  __shared__ float a1s[256];
  const int tid = threadIdx.x, blk = blockIdx.x;
  const int e = tid>>1, half = tid&1;
  size_t eg = (size_t)blk*128 + e;
  const float rx = rel[eg*3+0], ry = rel[eg*3+1], rz = rel[eg*3+2];
  if (tid < 64) stats1_to_lds(tid, mom, w1, b1, gamma, beta, a1s);
  __syncthreads();
  stage_H_core(e, half, rx, ry, rz, (const float*)a1s, Hh, Hl);
  __syncthreads();
  const int lane = tid & 63, wave = tid >> 6;
  const int col = lane & 15, quad = lane >> 4;
  LOAD_W_FRAGS()
  float b2v[4];
  #pragma unroll
  for (int r=0;r<4;r++) b2v[r] = b2[wave*16 + quad*4 + r];
  float ssum[4] = {0,0,0,0}, ssq[4] = {0,0,0,0};
  #pragma unroll
  for (int nt=0; nt<8; nt++){
    const int offB = (nt*16 + col)*72 + quad*8;
    bf16x8 bH0 = *(const bf16x8*)&Hh[offB];
    bf16x8 bH1 = *(const bf16x8*)&Hh[offB+32];
    bf16x8 bL0 = *(const bf16x8*)&Hl[offB];
    bf16x8 bL1 = *(const bf16x8*)&Hl[offB+32];
    f32x4 a = {0.f,0.f,0.f,0.f};
    MFMA6(a, bH0, bH1, bL0, bL1)
    #pragma unroll
    for (int r=0;r<4;r++){
      float t = a[r] + b2v[r];
      ssum[r] += t; ssq[r] += t*t;
    }
  }
  #pragma unroll
  for (int r=0;r<4;r++){
    ssum[r] = row_sum16(ssum[r]);
    ssq[r]  = row_sum16(ssq[r]);
  }
  if (col == 0){
    const int st = (blk & 31)*64;
    #pragma unroll
    for (int r=0;r<4;r++){
      int ch = wave*16 + quad*4 + r;
      atomicAdd(&gsum32[st+ch], ssum[r]);
      atomicAdd(&gsq32[st+ch],  ssq[r]);
    }
  }
}

// Pass 3 (MFMA): H1 -> g2 -> (BN2+relu) H2 -> g3 -> max over k.
// R18: DPP row-max replaces the 128 shuffle ops/thread in the k-reduce.
__global__ __launch_bounds__(256) void pass3_mfma(
    const float* __restrict__ rel,
    const float* __restrict__ mom, const float* __restrict__ w1,
    const float* __restrict__ b1, const float* __restrict__ gamma,
    const float* __restrict__ beta,
    const u16* __restrict__ w2h, const u16* __restrict__ w2l,
    const float* __restrict__ b2,
    const float* __restrict__ gsum32, const float* __restrict__ gsq32,
    float* __restrict__ out){
  __shared__ alignas(16) u16 Hh[128*72], Hl[128*72];
  __shared__ float a1s[256];
  __shared__ float s2s[64], c2s[64];
  const int tid = threadIdx.x, blk = blockIdx.x;
  const int e = tid>>1, half = tid&1;
  size_t eg = (size_t)blk*128 + e;
  const float rx = rel[eg*3+0], ry = rel[eg*3+1], rz = rel[eg*3+2];
  if (tid < 64){
    stats1_to_lds(tid, mom, w1, b1, gamma, beta, a1s);
  } else if (tid < 128){
    const int o = tid - 64;
    float s = 0.f, q = 0.f;
    #pragma unroll
    for (int i=0;i<32;i++){ s += gsum32[i*64+o]; q += gsq32[i*64+o]; }
    const float Minv = 1.0f / 524288.0f;
    float mu  = s*Minv;
    float var = q*Minv - mu*mu;
    float istd = rsqrtf(var + 1e-5f);
    float sc = gamma[o]*istd;
    float t2 = beta[o] - mu*sc;
    s2s[o] = sc;
    c2s[o] = fmaf(sc, b2[o], t2);
  }
  __syncthreads();
  stage_H_core(e, half, rx, ry, rz, (const float*)a1s, Hh, Hl);
  __syncthreads();
  const int lane = tid & 63, wave = tid >> 6;
  const int col = lane & 15, quad = lane >> 4;
  LOAD_W_FRAGS()
  float s2v[4], c2v[4], b2v[4];
  #pragma unroll
  for (int r=0;r<4;r++){
    int ch = wave*16 + quad*4 + r;
    s2v[r] = s2s[ch]; c2v[r] = c2s[ch]; b2v[r] = b2[ch];
  }
  f32x4 acc[8];
  #pragma unroll
  for (int nt=0; nt<8; nt++){
    const int offB = (nt*16 + col)*72 + quad*8;
    bf16x8 bH0 = *(const bf16x8*)&Hh[offB];
    bf16x8 bH1 = *(const bf16x8*)&Hh[offB+32];
    bf16x8 bL0 = *(const bf16x8*)&Hl[offB];
    bf16x8 bL1 = *(const bf16x8*)&Hl[offB+32];
    f32x4 a = {0.f,0.f,0.f,0.f};
    MFMA6(a, bH0, bH1, bL0, bL1)
    acc[nt] = a;
  }
  __syncthreads();   // all layer-2 H reads done -> safe to overwrite with H2
  #pragma unroll
  for (int nt=0; nt<8; nt++){
    const int eo = nt*16 + col;
    const int ch0 = wave*16 + quad*4;
    float h0, h1, h2, h3;
    {
      float g0 = acc[nt][0] + b2v[0];
      float g1 = acc[nt][1] + b2v[1];
      float g2 = acc[nt][2] + b2v[2];
      float g3 = acc[nt][3] + b2v[3];
      h0 = fmaxf(fmaf(g0, s2v[0], c2v[0]), 0.0f);
      h1 = fmaxf(fmaf(g1, s2v[1], c2v[1]), 0.0f);
      h2 = fmaxf(fmaf(g2, s2v[2], c2v[2]), 0.0f);
      h3 = fmaxf(fmaf(g3, s2v[3], c2v[3]), 0.0f);
    }
    u32 h01 = cvt_pk_bf16(h0, h1);
    u32 h23 = cvt_pk_bf16(h2, h3);
    float l0 = h0 - __uint_as_float(h01 << 16);
    float l1 = h1 - __uint_as_float(h01 & 0xFFFF0000u);
    float l2 = h2 - __uint_as_float(h23 << 16);
    float l3 = h3 - __uint_as_float(h23 & 0xFFFF0000u);
    u32 l01 = cvt_pk_bf16(l0, l1);
    u32 l23 = cvt_pk_bf16(l2, l3);
    *(uint2*)&Hh[eo*72 + ch0] = make_uint2(h01, h23);
    *(uint2*)&Hl[eo*72 + ch0] = make_uint2(l01, l23);
  }
  __syncthreads();
  #pragma unroll
  for (int nt=0; nt<8; nt++){
    const int offB = (nt*16 + col)*72 + quad*8;
    bf16x8 bH0 = *(const bf16x8*)&Hh[offB];
    bf16x8 bH1 = *(const bf16x8*)&Hh[offB+32];
    bf16x8 bL0 = *(const bf16x8*)&Hl[offB];
    bf16x8 bL1 = *(const bf16x8*)&Hl[offB+32];
    f32x4 a = {0.f,0.f,0.f,0.f};
    MFMA6(a, bH0, bH1, bL0, bL1)
    acc[nt][0] = row_max16(a[0]+b2v[0]);
    acc[nt][1] = row_max16(a[1]+b2v[1]);
    acc[nt][2] = row_max16(a[2]+b2v[2]);
    acc[nt][3] = row_max16(a[3]+b2v[3]);
  }
  if (col == 0){
    const int bb = blk >> 9;
    const int n0 = (blk & 511) * 8;
    #pragma unroll
    for (int r=0;r<4;r++){
      const int ch = wave*16 + quad*4 + r;
      float* po = out + (((size_t)bb*64 + ch) << 12) + n0;
      f32x4 v0 = {acc[0][r], acc[1][r], acc[2][r], acc[3][r]};
      f32x4 v1 = {acc[4][r], acc[5][r], acc[6][r], acc[7][r]};
      *(f32x4*)po = v0;
      *((f32x4*)po + 1) = v1;
    }
  }
}

extern "C" void kernel_launch(void* const* d_in, const int* in_sizes, int n_in,
                              void* d_out, int out_size, void* d_ws, size_t ws_size,
                              hipStream_t stream){
  const float* xyz   = (const float*)d_in[0];
  const float* w1    = (const float*)d_in[1];
  const float* b1    = (const float*)d_in[2];
  const float* w2    = (const float*)d_in[3];
  const float* b2    = (const float*)d_in[4];
  const float* gamma = (const float*)d_in[5];
  const float* beta  = (const float*)d_in[6];
  float* out = (float*)d_out;
  float* ws  = (float*)d_ws;

  float*  rel    = ws + REL_OFF;
  float4* pts4   = (float4*)(ws + PTS4_OFF);
  float*  mom    = ws + ACC_OFF;       // 16, zeroed in prep

  const bool big = ws_size >= (size_t)EXT_END * sizeof(float);
  u16 *w2h, *w2l; float *gsum32, *gsq32;
  if (big){
    w2h    = (u16*)(ws + EXT_OFF);
    w2l    = (u16*)(ws + EXT_OFF + 2048);
    gsum32 = ws + EXT_OFF + 4096;
    gsq32  = ws + EXT_OFF + 6144;
  } else {
    w2h    = (u16*)(ws + PTS4_OFF);
    w2l    = (u16*)(ws + PTS4_OFF + 2048);
    gsum32 = ws + PTS4_OFF + 4096;
    gsq32  = ws + PTS4_OFF + 6144;
  }

  prep_kernel  <<<128,  256, 0, stream>>>(xyz, pts4, mom, w2, w2h, w2l,
                                          gsum32, gsq32, big ? 1 : 0);
  knn_kernel   <<<1024, 256, 0, stream>>>(pts4, rel, mom);
  if (!big)
    w2prep_kernel<<<16, 256, 0, stream>>>(w2, w2h, w2l, gsum32, gsq32);
  pass2_mfma   <<<4096, 256, 0, stream>>>(rel, mom, w1, b1, gamma, beta,
                                          w2h, w2l, b2, gsum32, gsq32);
  pass3_mfma   <<<4096, 256, 0, stream>>>(rel, mom, w1, b1, gamma, beta,
                                          w2h, w2l, b2, gsum32, gsq32, out);
}